// Round 5
// baseline (508.612 us; speedup 1.0000x reference)
//
#include <hip/hip_runtime.h>
#include <cfloat>
#include <cmath>

#define NB_CODE 1024
#define CODE_DIM 64
#define NROWS (32 * 8192)          // N*T = 262144
#define NTC ((size_t)NROWS * CODE_DIM)
#define TAU 0.15f                  // >= ~6 sigma of (dropped xh*cl term + 6-bit packing) error

typedef __attribute__((ext_vector_type(8))) short short8;
typedef __attribute__((ext_vector_type(4))) float f32x4;

// ws layout (32-bit words):
//   0..1023      counts (u32)
//   1024         loss_sum (f32 atomic)
//   1025         flag_count (u32)
//   1026..1027   pad
//   1028..2051   cnorm f32[1024]
//   2052..34819  cbh: fragment-major bf16-hi of (-2*cb), 128 KB
//                entry e = ((T*2 + f)*64 + lane), 16B each (T = code tile 0..63)
//   34820..      flaglist u32[] (row<<10 | oldj)
#define W_LOSS 1024
#define W_FLAGCNT 1025
#define W_CNORM 1028
#define W_CBH 2052
#define W_FLAGLIST 34820

__device__ inline unsigned short f2bf_rne(float x) {
    unsigned int u = __float_as_uint(x);
    unsigned int r = (u + 0x7FFFu + ((u >> 16) & 1u)) >> 16;
    return (unsigned short)r;
}
__device__ inline float bf2f(unsigned short h) {
    return __uint_as_float(((unsigned int)h) << 16);
}
__device__ inline float unmask6(float v) {
    return __uint_as_float(__float_as_uint(v) & 0xFFFFFFC0u);
}

// ---- prep: cnorm + fragment-major bf16-hi split of (-2*codebook) ----
// B-frag (16x16x32): lane = lg*16+li holds col=li, k = 32*f + 8*lg + i.
__global__ void prep_kernel(const float* __restrict__ cb, float* __restrict__ ws) {
    int j = blockIdx.x * blockDim.x + threadIdx.x;
    if (j >= NB_CODE) return;
    float* cnorm = ws + W_CNORM;
    unsigned short* cbh = (unsigned short*)(ws + W_CBH);
    const int t = j >> 4, li = j & 15;

    float c2v[CODE_DIM];
    const float4* c4 = reinterpret_cast<const float4*>(cb + (size_t)j * CODE_DIM);
    float s = 0.f;
#pragma unroll
    for (int q = 0; q < 16; ++q) {
        float4 v = c4[q];
        float e[4] = {v.x, v.y, v.z, v.w};
#pragma unroll
        for (int u = 0; u < 4; ++u) {
            s = fmaf(e[u], e[u], s);
            c2v[q * 4 + u] = -2.f * e[u];
        }
    }
    cnorm[j] = s;

#pragma unroll
    for (int f = 0; f < 2; ++f) {
#pragma unroll
        for (int lg = 0; lg < 4; ++lg) {
            short8 h8;
#pragma unroll
            for (int i = 0; i < 8; ++i)
                h8[i] = (short)f2bf_rne(c2v[32 * f + 8 * lg + i]);
            size_t e = ((size_t)(t * 2 + f) * 64 + lg * 16 + li);
            *reinterpret_cast<short8*>(cbh + e * 8) = h8;
        }
    }
}

// ---- main: LDS-staged MFMA distance + packed argmin + dequant + stats ----
__global__ __launch_bounds__(512, 4) void vq_mfma_kernel(
    const float* __restrict__ x, const float* __restrict__ cb,
    float* __restrict__ ws, float* __restrict__ out, unsigned int flag_cap)
{
    __shared__ short8 sB[4096];      // 64 KB: one half of codebook-hi fragments
    __shared__ float scn[NB_CODE];   // 4 KB
    __shared__ int lds_j[8 * 64];    // 2 KB

    const int tid = threadIdx.x;
    const int w = tid >> 6, lane = tid & 63;
    const int lg = lane >> 4;
    const int li = lane & 15;
    const int wavebase = blockIdx.x * 512 + w * 64;

    const float* cnorm_g = ws + W_CNORM;
    const short8* cbh_v = (const short8*)(ws + W_CBH);
    unsigned int* counts = (unsigned int*)ws;
    float* loss_sum = ws + W_LOSS;
    unsigned int* flagcnt = (unsigned int*)ws + W_FLAGCNT;
    unsigned int* flaglist = (unsigned int*)ws + W_FLAGLIST;

    // --- load x rows, split to bf16 hi/lo fragments; accumulate sum(x^2) ---
    // A-frag (16x16x32): row = lane&15, k = 32*f + 8*(lane>>4) + i
    short8 ah[4][2], al[4][2];
    float x2sum = 0.f;
#pragma unroll
    for (int rt = 0; rt < 4; ++rt) {
        const float* xr = x + (size_t)(wavebase + rt * 16 + li) * CODE_DIM;
#pragma unroll
        for (int f = 0; f < 2; ++f) {
            const float4* p = reinterpret_cast<const float4*>(xr + 32 * f + 8 * lg);
            float4 v0 = p[0], v1 = p[1];
            float e[8] = {v0.x, v0.y, v0.z, v0.w, v1.x, v1.y, v1.z, v1.w};
            short8 h8, l8;
#pragma unroll
            for (int i = 0; i < 8; ++i) {
                float xe = e[i];
                x2sum = fmaf(xe, xe, x2sum);
                unsigned short hb = f2bf_rne(xe);
                h8[i] = (short)hb;
                l8[i] = (short)f2bf_rne(xe - bf2f(hb));
            }
            ah[rt][f] = h8;
            al[rt][f] = l8;
        }
    }

    float best[4][4], second[4][4];
#pragma unroll
    for (int rt = 0; rt < 4; ++rt)
#pragma unroll
        for (int r = 0; r < 4; ++r) { best[rt][r] = FLT_MAX; second[rt][r] = FLT_MAX; }

    // --- two halves of the codebook, each staged into LDS ---
    for (int h = 0; h < 2; ++h) {
        __syncthreads();   // h=1: all waves done reading half 0
        for (int i = tid; i < 4096; i += 512) sB[i] = cbh_v[h * 4096 + i];
        if (h == 0)
            for (int i = tid; i < NB_CODE; i += 512) scn[i] = cnorm_g[i];
        __syncthreads();

        for (int tl = 0; tl < 32; ++tl) {
            const int T = h * 32 + tl;                    // global tile 0..63 (6 bits)
            short8 b0 = sB[(tl * 2 + 0) * 64 + lane];
            short8 b1 = sB[(tl * 2 + 1) * 64 + lane];
            float cn = scn[T * 16 + li];
            f32x4 ci = {cn, cn, cn, cn};                  // init with ||c||^2
#pragma unroll
            for (int rt = 0; rt < 4; ++rt) {
                f32x4 acc = __builtin_amdgcn_mfma_f32_16x16x32_bf16(ah[rt][0], b0, ci, 0, 0, 0);
                acc = __builtin_amdgcn_mfma_f32_16x16x32_bf16(ah[rt][1], b1, acc, 0, 0, 0);
                acc = __builtin_amdgcn_mfma_f32_16x16x32_bf16(al[rt][0], b0, acc, 0, 0, 0);
                acc = __builtin_amdgcn_mfma_f32_16x16x32_bf16(al[rt][1], b1, acc, 0, 0, 0);
#pragma unroll
                for (int r = 0; r < 4; ++r) {
                    // pack tile index into mantissa LSBs: monotone, ties flagged later
                    float p = __uint_as_float((__float_as_uint(acc[r]) & 0xFFFFFFC0u) | (unsigned)T);
                    float mx = fmaxf(best[rt][r], p);
                    second[rt][r] = fminf(second[rt][r], mx);
                    best[rt][r] = fminf(best[rt][r], p);
                }
            }
        }
    }

    // --- per-row reduce across the 16 lanes of each group ---
    int codef[4][4];
#pragma unroll
    for (int rt = 0; rt < 4; ++rt)
#pragma unroll
        for (int r = 0; r < 4; ++r) {
            float b = best[rt][r], s = second[rt][r];
            int code = ((int)(__float_as_uint(b) & 63u) << 4) | li;
#pragma unroll
            for (int m = 1; m <= 8; m <<= 1) {
                float ob = __shfl_xor(b, m, 64);
                float os = __shfl_xor(s, m, 64);
                int   oc = __shfl_xor(code, m, 64);
                s = fminf(fminf(s, os), fmaxf(b, ob));
                bool take = (ob < b) || (ob == b && oc < code);
                if (take) { b = ob; code = oc; }
            }
            best[rt][r] = b; second[rt][r] = s; codef[rt][r] = code;
        }

    // --- stats, flags, stash indices ---
    float lsum = x2sum;
    if (li == 0) {
#pragma unroll
        for (int rt = 0; rt < 4; ++rt)
#pragma unroll
            for (int r = 0; r < 4; ++r) {
                int rowin = rt * 16 + lg * 4 + r;
                int j = codef[rt][r];
                lds_j[w * 64 + rowin] = j;
                atomicAdd(&counts[j], 1u);
                float bd = unmask6(best[rt][r]);
                lsum += bd;                       // loss_row = ||x||^2 + (||c||^2 - 2 x.c)
                if (unmask6(second[rt][r]) - bd <= TAU) {
                    unsigned pos = atomicAdd(flagcnt, 1u);
                    if (pos < flag_cap)
                        flaglist[pos] = ((unsigned)(wavebase + rowin) << 10) | (unsigned)j;
                }
            }
    }
#pragma unroll
    for (int m = 32; m >= 1; m >>= 1) lsum += __shfl_down(lsum, m, 64);
    if (lane == 0) atomicAdd(loss_sum, lsum);

    __syncthreads();

    // --- dequant write: 4 rows/iter, float4 per lane ---
    for (int it = 0; it < 16; ++it) {
        int rowin = it * 4 + lg;
        int j = lds_j[w * 64 + rowin];
        float4 v = *reinterpret_cast<const float4*>(cb + (size_t)j * CODE_DIM + li * 4);
        *reinterpret_cast<float4*>(out + (size_t)(wavebase + rowin) * CODE_DIM + li * 4) = v;
    }
}

// ---- exact f32 re-solve for flagged (near-tie) rows: one wave per row ----
__global__ __launch_bounds__(256) void fixup_kernel(
    const float* __restrict__ x, const float* __restrict__ cb,
    float* __restrict__ ws, float* __restrict__ out, unsigned int flag_cap)
{
    unsigned nf = *((unsigned*)ws + W_FLAGCNT);
    if (nf > flag_cap) nf = flag_cap;
    const float* cnorm = ws + W_CNORM;
    unsigned* flaglist = (unsigned*)ws + W_FLAGLIST;
    unsigned* counts = (unsigned*)ws;

    const int lane = threadIdx.x & 63;
    const unsigned wave_id = (blockIdx.x * blockDim.x + threadIdx.x) >> 6;
    const unsigned nwaves = (gridDim.x * blockDim.x) >> 6;

    for (unsigned idx = wave_id; idx < nf; idx += nwaves) {
        unsigned e = flaglist[idx];
        int row = (int)(e >> 10);
        int oldj = (int)(e & 1023u);

        float xr[CODE_DIM];
        const float4* x4 = reinterpret_cast<const float4*>(x + (size_t)row * CODE_DIM);
#pragma unroll
        for (int q = 0; q < 16; ++q) {
            float4 v = x4[q];
            xr[4 * q + 0] = v.x; xr[4 * q + 1] = v.y;
            xr[4 * q + 2] = v.z; xr[4 * q + 3] = v.w;
        }

        float bestv = FLT_MAX; int bj = 0x7fffffff;
        for (int t = 0; t < 16; ++t) {
            int j = lane * 16 + t;     // ascending within lane -> first occurrence kept
            const float* c = cb + (size_t)j * CODE_DIM;
            float d0 = 0.f, d1 = 0.f, d2 = 0.f, d3 = 0.f;
#pragma unroll
            for (int k = 0; k < CODE_DIM; k += 4) {
                d0 = fmaf(xr[k + 0], c[k + 0], d0);
                d1 = fmaf(xr[k + 1], c[k + 1], d1);
                d2 = fmaf(xr[k + 2], c[k + 2], d2);
                d3 = fmaf(xr[k + 3], c[k + 3], d3);
            }
            float dist = fmaf(-2.f, (d0 + d1) + (d2 + d3), cnorm[j]);
            if (dist < bestv) { bestv = dist; bj = j; }
        }
#pragma unroll
        for (int m = 1; m <= 32; m <<= 1) {
            float ob = __shfl_xor(bestv, m, 64);
            int   oj = __shfl_xor(bj, m, 64);
            bool take = (ob < bestv) || (ob == bestv && oj < bj);
            if (take) { bestv = ob; bj = oj; }
        }

        if (bj != oldj) {
            if (lane < 16) {
                *reinterpret_cast<float4*>(out + (size_t)row * CODE_DIM + lane * 4) =
                    *reinterpret_cast<const float4*>(cb + (size_t)bj * CODE_DIM + lane * 4);
            }
            if (lane == 0) {
                atomicAdd(&counts[bj], 1u);
                atomicAdd(&counts[oldj], (unsigned)-1);
            }
        }
    }
}

__global__ void finalize_kernel(const unsigned int* __restrict__ counts,
                                const float* __restrict__ loss_sum,
                                float* __restrict__ out)
{
    __shared__ float red[NB_CODE];
    int t = threadIdx.x;
    float p = (float)counts[t] / (float)NROWS;
    red[t] = p * logf(p + 1e-7f);
    __syncthreads();
    for (int s = NB_CODE / 2; s > 0; s >>= 1) {
        if (t < s) red[t] += red[t + s];
        __syncthreads();
    }
    if (t == 0) {
        out[NTC + 0] = *loss_sum / (float)NTC;
        out[NTC + 1] = expf(-red[0]);
    }
}

extern "C" void kernel_launch(void* const* d_in, const int* in_sizes, int n_in,
                              void* d_out, int out_size, void* d_ws, size_t ws_size,
                              hipStream_t stream) {
    const float* x  = (const float*)d_in[0];
    const float* cb = (const float*)d_in[1];
    float* out = (float*)d_out;
    float* ws = (float*)d_ws;

    unsigned flag_cap = 0;
    size_t words = ws_size / 4;
    if (words > (size_t)W_FLAGLIST) flag_cap = (unsigned)(words - W_FLAGLIST);
    if (flag_cap > NROWS) flag_cap = NROWS;

    // zero counts + loss + flagcnt each call (ws not re-poisoned between replays)
    hipMemsetAsync(d_ws, 0, 1028 * sizeof(float), stream);

    prep_kernel<<<NB_CODE / 256, 256, 0, stream>>>(cb, ws);
    vq_mfma_kernel<<<NROWS / 512, 512, 0, stream>>>(x, cb, ws, out, flag_cap);
    fixup_kernel<<<768, 256, 0, stream>>>(x, cb, ws, out, flag_cap);
    finalize_kernel<<<1, NB_CODE, 0, stream>>>((unsigned int*)ws, ws + W_LOSS, out);
}

// Round 6
// 272.865 us; speedup vs baseline: 1.8640x; 1.8640x over previous
//
#include <hip/hip_runtime.h>
#include <cfloat>
#include <cmath>

#define NB_CODE 1024
#define CODE_DIM 64
#define NROWS (32 * 8192)          // N*T = 262144
#define NTC ((size_t)NROWS * CODE_DIM)
#define TAU 0.02f                  // ~8x the (lo*lo dropped + 6-bit packing) error bound

typedef __attribute__((ext_vector_type(8))) short short8;
typedef __attribute__((ext_vector_type(4))) float f32x4;

// ws layout (32-bit words):
//   0..1023      counts (u32)
//   1024         loss_sum (f32 atomic)
//   1025         flag_count (u32)
//   1026..1027   pad
//   1028..2051   cnorm f32[1024]
//   2052..67587  cbp: fragment-major bf16 split of (-2*cb), 256 KB
//                entry e = ((T*4 + chunk)*64 + lane), 16B each (T = tile 0..63)
//                chunk 0,1 = hi (k 0..31 / 32..63), chunk 2,3 = lo
//   67588..      flaglist u32[] (row<<10 | oldj)
#define W_LOSS 1024
#define W_FLAGCNT 1025
#define W_CNORM 1028
#define W_CBP 2052
#define W_FLAGLIST 67588

__device__ inline unsigned short f2bf_rne(float x) {
    unsigned int u = __float_as_uint(x);
    unsigned int r = (u + 0x7FFFu + ((u >> 16) & 1u)) >> 16;
    return (unsigned short)r;
}
__device__ inline float bf2f(unsigned short h) {
    return __uint_as_float(((unsigned int)h) << 16);
}
__device__ inline float unmask6(float v) {
    return __uint_as_float(__float_as_uint(v) & 0xFFFFFFC0u);
}

// ---- prep: cnorm + fragment-major bf16 hi/lo split of (-2*codebook) ----
// B-frag (16x16x32): lane = lg*16+li holds col=li, k = 32*f + 8*lg + i.
__global__ void prep_kernel(const float* __restrict__ cb, float* __restrict__ ws) {
    int j = blockIdx.x * blockDim.x + threadIdx.x;
    if (j >= NB_CODE) return;
    float* cnorm = ws + W_CNORM;
    unsigned short* cbp = (unsigned short*)(ws + W_CBP);
    const int t = j >> 4, li = j & 15;

    float c2v[CODE_DIM];
    const float4* c4 = reinterpret_cast<const float4*>(cb + (size_t)j * CODE_DIM);
    float s = 0.f;
#pragma unroll
    for (int q = 0; q < 16; ++q) {
        float4 v = c4[q];
        float e[4] = {v.x, v.y, v.z, v.w};
#pragma unroll
        for (int u = 0; u < 4; ++u) {
            s = fmaf(e[u], e[u], s);
            c2v[q * 4 + u] = -2.f * e[u];
        }
    }
    cnorm[j] = s;

#pragma unroll
    for (int f = 0; f < 2; ++f) {
#pragma unroll
        for (int lg = 0; lg < 4; ++lg) {
            short8 h8, l8;
#pragma unroll
            for (int i = 0; i < 8; ++i) {
                float c2 = c2v[32 * f + 8 * lg + i];
                unsigned short hb = f2bf_rne(c2);
                h8[i] = (short)hb;
                l8[i] = (short)f2bf_rne(c2 - bf2f(hb));
            }
            size_t ehi = ((size_t)(t * 4 + f) * 64 + lg * 16 + li);
            size_t elo = ((size_t)(t * 4 + 2 + f) * 64 + lg * 16 + li);
            *reinterpret_cast<short8*>(cbp + ehi * 8) = h8;
            *reinterpret_cast<short8*>(cbp + elo * 8) = l8;
        }
    }
}

// ---- main: LDS-staged MFMA distance + packed argmin + dequant + stats ----
// 512 threads = 8 waves, 32 rows/wave (rt=2) -> 256 rows/block, 1024 blocks.
// LDS: 64KB stage (16 tiles x 4 chunks) + 4KB cnorm + 1KB idx = 69KB -> 2 blocks/CU.
__global__ __launch_bounds__(512, 4) void vq_mfma_kernel(
    const float* __restrict__ x, const float* __restrict__ cb,
    float* __restrict__ ws, float* __restrict__ out, unsigned int flag_cap)
{
    __shared__ short8 sB[4096];      // 64 KB: 16 tiles of B fragments (hi+lo)
    __shared__ float scn[NB_CODE];   // 4 KB
    __shared__ int lds_j[256];       // 1 KB

    const int tid = threadIdx.x;
    const int w = tid >> 6, lane = tid & 63;
    const int lg = lane >> 4;
    const int li = lane & 15;
    const int wavebase = blockIdx.x * 256 + w * 32;

    const float* cnorm_g = ws + W_CNORM;
    const short8* cbp_v = (const short8*)(ws + W_CBP);
    unsigned int* counts = (unsigned int*)ws;
    float* loss_sum = ws + W_LOSS;
    unsigned int* flagcnt = (unsigned int*)ws + W_FLAGCNT;
    unsigned int* flaglist = (unsigned int*)ws + W_FLAGLIST;

    // --- load x rows, split to bf16 hi/lo fragments; accumulate sum(x^2) ---
    // A-frag (16x16x32): row = lane&15, k = 32*f + 8*(lane>>4) + i
    short8 ah[2][2], al[2][2];
    float x2sum = 0.f;
#pragma unroll
    for (int rt = 0; rt < 2; ++rt) {
        const float* xr = x + (size_t)(wavebase + rt * 16 + li) * CODE_DIM;
#pragma unroll
        for (int f = 0; f < 2; ++f) {
            const float4* p = reinterpret_cast<const float4*>(xr + 32 * f + 8 * lg);
            float4 v0 = p[0], v1 = p[1];
            float e[8] = {v0.x, v0.y, v0.z, v0.w, v1.x, v1.y, v1.z, v1.w};
            short8 h8, l8;
#pragma unroll
            for (int i = 0; i < 8; ++i) {
                float xe = e[i];
                x2sum = fmaf(xe, xe, x2sum);
                unsigned short hb = f2bf_rne(xe);
                h8[i] = (short)hb;
                l8[i] = (short)f2bf_rne(xe - bf2f(hb));
            }
            ah[rt][f] = h8;
            al[rt][f] = l8;
        }
    }

    for (int i = tid; i < NB_CODE; i += 512) scn[i] = cnorm_g[i];

    float best[2][4], second[2][4];
#pragma unroll
    for (int rt = 0; rt < 2; ++rt)
#pragma unroll
        for (int r = 0; r < 4; ++r) { best[rt][r] = FLT_MAX; second[rt][r] = FLT_MAX; }

    // --- 4 phases x 16 tiles, B staged through LDS ---
    for (int ph = 0; ph < 4; ++ph) {
        if (ph) __syncthreads();                 // waves done reading previous phase
        for (int i = tid; i < 4096; i += 512) sB[i] = cbp_v[ph * 4096 + i];
        __syncthreads();

        for (int tl = 0; tl < 16; ++tl) {
            const int T = ph * 16 + tl;          // global tile id (6 bits)
            short8 b0 = sB[(tl * 4 + 0) * 64 + lane];   // hi k0..31
            short8 b1 = sB[(tl * 4 + 1) * 64 + lane];   // hi k32..63
            short8 b2 = sB[(tl * 4 + 2) * 64 + lane];   // lo k0..31
            short8 b3 = sB[(tl * 4 + 3) * 64 + lane];   // lo k32..63
            float cn = scn[T * 16 + li];
            f32x4 ci = {cn, cn, cn, cn};                // init with ||c||^2
#pragma unroll
            for (int rt = 0; rt < 2; ++rt) {
                // (xh+xl)*ch + xh*cl  (lo*lo dropped, ~1e-3)
                f32x4 acc = __builtin_amdgcn_mfma_f32_16x16x32_bf16(ah[rt][0], b0, ci, 0, 0, 0);
                acc = __builtin_amdgcn_mfma_f32_16x16x32_bf16(ah[rt][1], b1, acc, 0, 0, 0);
                acc = __builtin_amdgcn_mfma_f32_16x16x32_bf16(al[rt][0], b0, acc, 0, 0, 0);
                acc = __builtin_amdgcn_mfma_f32_16x16x32_bf16(al[rt][1], b1, acc, 0, 0, 0);
                acc = __builtin_amdgcn_mfma_f32_16x16x32_bf16(ah[rt][0], b2, acc, 0, 0, 0);
                acc = __builtin_amdgcn_mfma_f32_16x16x32_bf16(ah[rt][1], b3, acc, 0, 0, 0);
#pragma unroll
                for (int r = 0; r < 4; ++r) {
                    // pack tile id into mantissa LSBs (monotone; ties flagged later)
                    float p = __uint_as_float((__float_as_uint(acc[r]) & 0xFFFFFFC0u) | (unsigned)T);
                    float mx = fmaxf(best[rt][r], p);
                    second[rt][r] = fminf(second[rt][r], mx);
                    best[rt][r] = fminf(best[rt][r], p);
                }
            }
        }
    }

    // --- per-row reduce across the 16 lanes of each group ---
    int codef[2][4];
#pragma unroll
    for (int rt = 0; rt < 2; ++rt)
#pragma unroll
        for (int r = 0; r < 4; ++r) {
            float b = best[rt][r], s = second[rt][r];
            int code = ((int)(__float_as_uint(b) & 63u) << 4) | li;
#pragma unroll
            for (int m = 1; m <= 8; m <<= 1) {
                float ob = __shfl_xor(b, m, 64);
                float os = __shfl_xor(s, m, 64);
                int   oc = __shfl_xor(code, m, 64);
                s = fminf(fminf(s, os), fmaxf(b, ob));
                bool take = (ob < b) || (ob == b && oc < code);
                if (take) { b = ob; code = oc; }
            }
            best[rt][r] = b; second[rt][r] = s; codef[rt][r] = code;
        }

    // --- stats, flags, stash indices ---
    float lsum = x2sum;
    if (li == 0) {
#pragma unroll
        for (int rt = 0; rt < 2; ++rt)
#pragma unroll
            for (int r = 0; r < 4; ++r) {
                int rowin = rt * 16 + lg * 4 + r;
                int j = codef[rt][r];
                lds_j[w * 32 + rowin] = j;
                atomicAdd(&counts[j], 1u);
                float bd = unmask6(best[rt][r]);
                lsum += bd;                    // loss_row = ||x||^2 + (||c||^2 - 2 x.c)
                if (unmask6(second[rt][r]) - bd <= TAU) {
                    unsigned pos = atomicAdd(flagcnt, 1u);
                    if (pos < flag_cap)
                        flaglist[pos] = ((unsigned)(wavebase + rowin) << 10) | (unsigned)j;
                }
            }
    }
#pragma unroll
    for (int m = 32; m >= 1; m >>= 1) lsum += __shfl_down(lsum, m, 64);
    if (lane == 0) atomicAdd(loss_sum, lsum);

    __syncthreads();

    // --- dequant write: 4 rows/iter, float4 per lane ---
    for (int it = 0; it < 8; ++it) {
        int rowin = it * 4 + lg;
        int j = lds_j[w * 32 + rowin];
        float4 v = *reinterpret_cast<const float4*>(cb + (size_t)j * CODE_DIM + li * 4);
        *reinterpret_cast<float4*>(out + (size_t)(wavebase + rowin) * CODE_DIM + li * 4) = v;
    }
}

// ---- exact f32 re-solve for flagged (near-tie) rows: one wave per row ----
__global__ __launch_bounds__(256) void fixup_kernel(
    const float* __restrict__ x, const float* __restrict__ cb,
    float* __restrict__ ws, float* __restrict__ out, unsigned int flag_cap)
{
    unsigned nf = *((unsigned*)ws + W_FLAGCNT);
    if (nf > flag_cap) nf = flag_cap;
    const float* cnorm = ws + W_CNORM;
    unsigned* flaglist = (unsigned*)ws + W_FLAGLIST;
    unsigned* counts = (unsigned*)ws;

    const int lane = threadIdx.x & 63;
    const unsigned wave_id = (blockIdx.x * blockDim.x + threadIdx.x) >> 6;
    const unsigned nwaves = (gridDim.x * blockDim.x) >> 6;

    for (unsigned idx = wave_id; idx < nf; idx += nwaves) {
        unsigned e = flaglist[idx];
        int row = (int)(e >> 10);
        int oldj = (int)(e & 1023u);

        float xr[CODE_DIM];
        const float4* x4 = reinterpret_cast<const float4*>(x + (size_t)row * CODE_DIM);
#pragma unroll
        for (int q = 0; q < 16; ++q) {
            float4 v = x4[q];
            xr[4 * q + 0] = v.x; xr[4 * q + 1] = v.y;
            xr[4 * q + 2] = v.z; xr[4 * q + 3] = v.w;
        }

        float bestv = FLT_MAX; int bj = 0x7fffffff;
        for (int t = 0; t < 16; ++t) {
            int j = lane * 16 + t;     // ascending within lane -> first occurrence kept
            const float* c = cb + (size_t)j * CODE_DIM;
            float d0 = 0.f, d1 = 0.f, d2 = 0.f, d3 = 0.f;
#pragma unroll
            for (int k = 0; k < CODE_DIM; k += 4) {
                d0 = fmaf(xr[k + 0], c[k + 0], d0);
                d1 = fmaf(xr[k + 1], c[k + 1], d1);
                d2 = fmaf(xr[k + 2], c[k + 2], d2);
                d3 = fmaf(xr[k + 3], c[k + 3], d3);
            }
            float dist = fmaf(-2.f, (d0 + d1) + (d2 + d3), cnorm[j]);
            if (dist < bestv) { bestv = dist; bj = j; }
        }
#pragma unroll
        for (int m = 1; m <= 32; m <<= 1) {
            float ob = __shfl_xor(bestv, m, 64);
            int   oj = __shfl_xor(bj, m, 64);
            bool take = (ob < bestv) || (ob == bestv && oj < bj);
            if (take) { bestv = ob; bj = oj; }
        }

        if (bj != oldj) {
            if (lane < 16) {
                *reinterpret_cast<float4*>(out + (size_t)row * CODE_DIM + lane * 4) =
                    *reinterpret_cast<const float4*>(cb + (size_t)bj * CODE_DIM + lane * 4);
            }
            if (lane == 0) {
                atomicAdd(&counts[bj], 1u);
                atomicAdd(&counts[oldj], (unsigned)-1);
            }
        }
    }
}

__global__ void finalize_kernel(const unsigned int* __restrict__ counts,
                                const float* __restrict__ loss_sum,
                                float* __restrict__ out)
{
    __shared__ float red[NB_CODE];
    int t = threadIdx.x;
    float p = (float)counts[t] / (float)NROWS;
    red[t] = p * logf(p + 1e-7f);
    __syncthreads();
    for (int s = NB_CODE / 2; s > 0; s >>= 1) {
        if (t < s) red[t] += red[t + s];
        __syncthreads();
    }
    if (t == 0) {
        out[NTC + 0] = *loss_sum / (float)NTC;
        out[NTC + 1] = expf(-red[0]);
    }
}

extern "C" void kernel_launch(void* const* d_in, const int* in_sizes, int n_in,
                              void* d_out, int out_size, void* d_ws, size_t ws_size,
                              hipStream_t stream) {
    const float* x  = (const float*)d_in[0];
    const float* cb = (const float*)d_in[1];
    float* out = (float*)d_out;
    float* ws = (float*)d_ws;

    unsigned flag_cap = 0;
    size_t words = ws_size / 4;
    if (words > (size_t)W_FLAGLIST) flag_cap = (unsigned)(words - W_FLAGLIST);
    if (flag_cap > NROWS) flag_cap = NROWS;

    // zero counts + loss + flagcnt each call (ws not re-poisoned between replays)
    hipMemsetAsync(d_ws, 0, 1028 * sizeof(float), stream);

    prep_kernel<<<NB_CODE / 256, 256, 0, stream>>>(cb, ws);
    vq_mfma_kernel<<<NROWS / 256, 512, 0, stream>>>(x, cb, ws, out, flag_cap);
    fixup_kernel<<<1024, 256, 0, stream>>>(x, cb, ws, out, flag_cap);
    finalize_kernel<<<1, NB_CODE, 0, stream>>>((unsigned int*)ws, ws + W_LOSS, out);
}